// Round 1
// baseline (407.464 us; speedup 1.0000x reference)
//
#include <hip/hip_runtime.h>
#include <hip/hip_bf16.h>

// MDN NLL: pi = softmax(t@Wg+bg); mean/logvar = x@W{m,v}+b; ll = gaussian LL;
// loss = -sum log(sum_k pi_k exp(ll_k)) + ||Wm||^2 + ||Wv||^2 + ||Wg||^2
//
// N=524288 Dx=128 Dt=64 M=32 K=8. Memory-bound: 470 MB reads -> ~75us floor.
// bf16 MFMA for the two batched matmuls; everything else fused per 64-row tile.

#define NN 524288
#define DX 128
#define DT 64
#define MDIM 32
#define KEXP 8
#define TILE_R 64
#define THREADS 512
#define GRID_MAIN 512
#define TILES_TOTAL (NN / TILE_R)          // 8192
#define TPB (TILES_TOTAL / GRID_MAIN)      // 16

typedef __bf16 bf16x8 __attribute__((ext_vector_type(8)));
typedef unsigned short u16x8 __attribute__((ext_vector_type(8)));
typedef float f32x4 __attribute__((ext_vector_type(4)));

__device__ __forceinline__ unsigned short f2bf(float f) {
  unsigned int u = __builtin_bit_cast(unsigned int, f);
  u += 0x7fffu + ((u >> 16) & 1u);         // RNE
  return (unsigned short)(u >> 16);
}

__global__ __launch_bounds__(THREADS, 2) void mdn_main(
    const float* __restrict__ x, const float* __restrict__ t,
    const float* __restrict__ y, const float* __restrict__ Wm,
    const float* __restrict__ bm, const float* __restrict__ Wv,
    const float* __restrict__ bv, const float* __restrict__ Wg,
    const float* __restrict__ bg, float* __restrict__ partials,
    float* __restrict__ out_atomic)
{
  // x tile as bf16, XOR-swizzled (row stride 256B -> 16-way conflict unswizzled)
  __shared__ unsigned short xs[TILE_R * DX];      // 16 KB
  __shared__ float wg_s[DT * KEXP];               // 2 KB
  __shared__ float bg_s[KEXP];
  __shared__ float ll_s[TILE_R][KEXP];            // 2 KB
  __shared__ float red_s[8];

  const int tid = threadIdx.x;
  const int lane = tid & 63;
  const int wv = tid >> 6;      // wave id == expert k
  const int l15 = lane & 15;
  const int lhi = lane >> 4;    // 0..3

  for (int i = tid; i < DT * KEXP; i += THREADS) wg_s[i] = Wg[i];
  if (tid < KEXP) bg_s[tid] = bg[tid];

  // per-lane biases for this wave's expert (m = l15 and l15+16)
  const float bm_lo = bm[wv * MDIM + l15];
  const float bm_hi = bm[wv * MDIM + 16 + l15];
  const float bv_lo = bv[wv * MDIM + l15];
  const float bv_hi = bv[wv * MDIM + 16 + l15];

  // B fragments held in registers for the whole kernel:
  // ct 0,1 = Wm cols m=0..15,16..31 ; ct 2,3 = Wv. kk = K-slice of 32.
  // B layout (16x16x32): k = (lane>>4)*8 + i, col = lane&15.
  bf16x8 bfrag[4][4];
  #pragma unroll
  for (int ct = 0; ct < 4; ++ct) {
    const float* W = (ct < 2 ? Wm : Wv) + (size_t)wv * (DX * MDIM);
    const int mcol = ((ct & 1) << 4) + l15;
    #pragma unroll
    for (int kk = 0; kk < 4; ++kk) {
      u16x8 tmp;
      #pragma unroll
      for (int i = 0; i < 8; ++i) {
        const int d = kk * 32 + lhi * 8 + i;
        tmp[i] = f2bf(W[d * MDIM + mcol]);
      }
      bfrag[ct][kk] = __builtin_bit_cast(bf16x8, tmp);
    }
  }

  const int srow = tid >> 3;   // staging: row per 8 threads
  const int seg = tid & 7;     // 16-float segment within row
  const int first = blockIdx.x * TPB;

  float4 v0, v1, v2, v3;       // async-stage registers (T14)
  auto issue_loads = [&](int tile) {
    const float* xr = x + (size_t)(tile * TILE_R + srow) * DX + seg * 16;
    v0 = ((const float4*)xr)[0];
    v1 = ((const float4*)xr)[1];
    v2 = ((const float4*)xr)[2];
    v3 = ((const float4*)xr)[3];
  };
  auto write_tile = [&]() {
    u16x8 c0, c1;
    c0[0]=f2bf(v0.x); c0[1]=f2bf(v0.y); c0[2]=f2bf(v0.z); c0[3]=f2bf(v0.w);
    c0[4]=f2bf(v1.x); c0[5]=f2bf(v1.y); c0[6]=f2bf(v1.z); c0[7]=f2bf(v1.w);
    c1[0]=f2bf(v2.x); c1[1]=f2bf(v2.y); c1[2]=f2bf(v2.z); c1[3]=f2bf(v2.w);
    c1[4]=f2bf(v3.x); c1[5]=f2bf(v3.y); c1[6]=f2bf(v3.z); c1[7]=f2bf(v3.w);
    const int swz = (srow & 7) << 4;
    const int b0 = srow * 256 + (((seg * 2) * 16) ^ swz);
    const int b1 = srow * 256 + (((seg * 2 + 1) * 16) ^ swz);
    *(u16x8*)((char*)xs + b0) = c0;
    *(u16x8*)((char*)xs + b1) = c1;
  };

  float loss_acc = 0.f;
  const float HL2PI = 0.91893853320467274f;   // 0.5*log(2*pi)

  issue_loads(first);
  write_tile();
  __syncthreads();

  for (int it = 0; it < TPB; ++it) {
    const int row0 = (first + it) * TILE_R;
    const int nt = (it + 1 < TPB) ? it + 1 : it;
    issue_loads(first + nt);   // issue early; consumed after gate barrier

    f32x4 acc[4][4];
    #pragma unroll
    for (int rt = 0; rt < 4; ++rt)
      #pragma unroll
      for (int ct = 0; ct < 4; ++ct)
        acc[rt][ct] = (f32x4){0.f, 0.f, 0.f, 0.f};

    // A layout (16x16x32): row = lane&15, k = (lane>>4)*8 + i
    #pragma unroll
    for (int kk = 0; kk < 4; ++kk) {
      bf16x8 afrag[4];
      #pragma unroll
      for (int rt = 0; rt < 4; ++rt) {
        const int r = rt * 16 + l15;
        const int c = kk * 4 + lhi;            // 16B chunk index within row
        const int byte = r * 256 + ((c * 16) ^ ((r & 7) << 4));
        afrag[rt] = *(const bf16x8*)((const char*)xs + byte);
      }
      #pragma unroll
      for (int rt = 0; rt < 4; ++rt)
        #pragma unroll
        for (int ct = 0; ct < 4; ++ct)
          acc[rt][ct] = __builtin_amdgcn_mfma_f32_16x16x32_bf16(
              afrag[rt], bfrag[ct][kk], acc[rt][ct], 0, 0, 0);
    }

    // epilogue: C/D layout col=lane&15, row=(lane>>4)*4+j (m89-verified).
    // same lane holds mean(k,m) and logvar(k,m) for the same row.
    #pragma unroll
    for (int rt = 0; rt < 4; ++rt) {
      #pragma unroll
      for (int j = 0; j < 4; ++j) {
        const int r = rt * 16 + lhi * 4 + j;
        const float* yr = y + (size_t)(row0 + r) * MDIM;
        const float y0 = yr[l15];
        const float y1 = yr[16 + l15];
        const float mean0 = acc[rt][0][j] + bm_lo;
        const float mean1 = acc[rt][1][j] + bm_hi;
        const float lv0 = acc[rt][2][j] + bv_lo;
        const float lv1 = acc[rt][3][j] + bv_hi;
        const float d0 = y0 - mean0, d1 = y1 - mean1;
        float s = d0 * d0 * (0.5f * __expf(-lv0)) + 0.5f * lv0
                + d1 * d1 * (0.5f * __expf(-lv1)) + 0.5f * lv1;
        s += __shfl_xor(s, 1);
        s += __shfl_xor(s, 2);
        s += __shfl_xor(s, 4);
        s += __shfl_xor(s, 8);
        if (l15 == 0) ll_s[r][wv] = -(s + MDIM * HL2PI);
      }
    }
    __syncthreads();

    // gate + mixture: thread (row = tid>>3, k = tid&7)
    // log(mix) = LSE_k(logit+ll) - LSE_k(logit)
    {
      const int r = tid >> 3;
      const int k = tid & 7;
      const float* tr = t + (size_t)(row0 + r) * DT;
      float logit = bg_s[k];
      #pragma unroll
      for (int d = 0; d < DT; d += 4) {
        const float4 tv = *(const float4*)(tr + d);
        logit += tv.x * wg_s[(d + 0) * KEXP + k];
        logit += tv.y * wg_s[(d + 1) * KEXP + k];
        logit += tv.z * wg_s[(d + 2) * KEXP + k];
        logit += tv.w * wg_s[(d + 3) * KEXP + k];
      }
      const float a = logit + ll_s[r][k];
      float mg = logit, ma = a;
      mg = fmaxf(mg, __shfl_xor(mg, 1));
      mg = fmaxf(mg, __shfl_xor(mg, 2));
      mg = fmaxf(mg, __shfl_xor(mg, 4));
      ma = fmaxf(ma, __shfl_xor(ma, 1));
      ma = fmaxf(ma, __shfl_xor(ma, 2));
      ma = fmaxf(ma, __shfl_xor(ma, 4));
      float eg = __expf(logit - mg);
      float ea = __expf(a - ma);
      eg += __shfl_xor(eg, 1); eg += __shfl_xor(eg, 2); eg += __shfl_xor(eg, 4);
      ea += __shfl_xor(ea, 1); ea += __shfl_xor(ea, 2); ea += __shfl_xor(ea, 4);
      if (k == 0) loss_acc += (mg + __logf(eg)) - (ma + __logf(ea));
    }
    __syncthreads();

    write_tile();      // xs fully consumed (MFMA phase); safe after barrier
    __syncthreads();
  }

  loss_acc += __shfl_xor(loss_acc, 1);
  loss_acc += __shfl_xor(loss_acc, 2);
  loss_acc += __shfl_xor(loss_acc, 4);
  loss_acc += __shfl_xor(loss_acc, 8);
  loss_acc += __shfl_xor(loss_acc, 16);
  loss_acc += __shfl_xor(loss_acc, 32);
  if (lane == 0) red_s[wv] = loss_acc;
  __syncthreads();
  if (tid == 0) {
    float s = 0.f;
    #pragma unroll
    for (int w = 0; w < 8; ++w) s += red_s[w];
    if (partials) partials[blockIdx.x] = s;
    else atomicAdd(out_atomic, s);
  }
}

__global__ void mdn_reg(const float* __restrict__ Wm, const float* __restrict__ Wv,
                        const float* __restrict__ Wg, float* __restrict__ partials,
                        float* __restrict__ out_atomic)
{
  __shared__ float red[4];
  const int gid = blockIdx.x * 256 + threadIdx.x;
  const int stride = 64 * 256;
  float s = 0.f;
  for (int i = gid; i < DX * MDIM * KEXP; i += stride) { float w = Wm[i]; s += w * w; }
  for (int i = gid; i < DX * MDIM * KEXP; i += stride) { float w = Wv[i]; s += w * w; }
  for (int i = gid; i < DT * KEXP; i += stride)        { float w = Wg[i]; s += w * w; }
  s += __shfl_xor(s, 1);
  s += __shfl_xor(s, 2);
  s += __shfl_xor(s, 4);
  s += __shfl_xor(s, 8);
  s += __shfl_xor(s, 16);
  s += __shfl_xor(s, 32);
  if ((threadIdx.x & 63) == 0) red[threadIdx.x >> 6] = s;
  __syncthreads();
  if (threadIdx.x == 0) {
    float b = red[0] + red[1] + red[2] + red[3];
    if (partials) partials[GRID_MAIN + blockIdx.x] = b;
    else atomicAdd(out_atomic, b);
  }
}

__global__ void mdn_final(const float* __restrict__ partials, float* __restrict__ out)
{
  __shared__ float red[4];
  float s = 0.f;
  for (int i = threadIdx.x; i < GRID_MAIN + 64; i += 256) s += partials[i];
  s += __shfl_xor(s, 1);
  s += __shfl_xor(s, 2);
  s += __shfl_xor(s, 4);
  s += __shfl_xor(s, 8);
  s += __shfl_xor(s, 16);
  s += __shfl_xor(s, 32);
  if ((threadIdx.x & 63) == 0) red[threadIdx.x >> 6] = s;
  __syncthreads();
  if (threadIdx.x == 0) out[0] = red[0] + red[1] + red[2] + red[3];
}

extern "C" void kernel_launch(void* const* d_in, const int* in_sizes, int n_in,
                              void* d_out, int out_size, void* d_ws, size_t ws_size,
                              hipStream_t stream)
{
  const float* x  = (const float*)d_in[0];
  const float* t  = (const float*)d_in[1];
  const float* y  = (const float*)d_in[2];
  const float* Wm = (const float*)d_in[3];
  const float* bm = (const float*)d_in[4];
  const float* Wv = (const float*)d_in[5];
  const float* bv = (const float*)d_in[6];
  const float* Wg = (const float*)d_in[7];
  const float* bg = (const float*)d_in[8];
  float* out = (float*)d_out;

  if (ws_size >= (GRID_MAIN + 64) * sizeof(float)) {
    float* partials = (float*)d_ws;
    mdn_main<<<GRID_MAIN, THREADS, 0, stream>>>(x, t, y, Wm, bm, Wv, bv, Wg, bg,
                                                partials, nullptr);
    mdn_reg<<<64, 256, 0, stream>>>(Wm, Wv, Wg, partials, nullptr);
    mdn_final<<<1, 256, 0, stream>>>(partials, out);
  } else {
    hipMemsetAsync(out, 0, sizeof(float), stream);
    mdn_main<<<GRID_MAIN, THREADS, 0, stream>>>(x, t, y, Wm, bm, Wv, bv, Wg, bg,
                                                nullptr, out);
    mdn_reg<<<64, 256, 0, stream>>>(Wm, Wv, Wg, nullptr, out);
  }
}

// Round 2
// 301.402 us; speedup vs baseline: 1.3519x; 1.3519x over previous
//
#include <hip/hip_runtime.h>
#include <hip/hip_bf16.h>

// MDN NLL, fully fused. N=524288 Dx=128 Dt=64 M=32 K=8.
// Memory-bound target: 470 MB reads -> ~75us floor at 6.3 TB/s.
// Pipeline: all inputs staged f32 via global_load_lds (dbuf, issued 1 iter
// ahead), raw s_barrier + manual waitcnt (no vmcnt drains mid-iter),
// source-pre-swizzled chunks for conflict-free ds_read_b128.

#define NN 524288
#define DX 128
#define DT 64
#define MDIM 32
#define KEXP 8
#define TILE_R 32
#define THREADS 512
#define GRID_MAIN 512
#define TILES_TOTAL (NN / TILE_R)        // 16384
#define TPB (TILES_TOTAL / GRID_MAIN)    // 32

typedef __bf16 bf16x8 __attribute__((ext_vector_type(8)));
typedef float f32x4 __attribute__((ext_vector_type(4)));

__device__ __forceinline__ void glds16(const float* g, float* l) {
  __builtin_amdgcn_global_load_lds(
      (const __attribute__((address_space(1))) unsigned int*)g,
      (__attribute__((address_space(3))) unsigned int*)l, 16, 0, 0);
}

__device__ __forceinline__ bf16x8 cvt8(const f32x4 a, const f32x4 b) {
  bf16x8 r;
  r[0] = (__bf16)a[0]; r[1] = (__bf16)a[1]; r[2] = (__bf16)a[2]; r[3] = (__bf16)a[3];
  r[4] = (__bf16)b[0]; r[5] = (__bf16)b[1]; r[6] = (__bf16)b[2]; r[7] = (__bf16)b[3];
  return r;
}

#define MFMA16(a, b, c) __builtin_amdgcn_mfma_f32_16x16x32_bf16(a, b, c, 0, 0, 0)

// Raw barriers: keep DMA in flight where safe (rule 18: sched_barrier after).
#define B_FULL() do { \
  asm volatile("s_waitcnt vmcnt(0) lgkmcnt(0)" ::: "memory"); \
  __builtin_amdgcn_s_barrier(); \
  __builtin_amdgcn_sched_barrier(0); } while (0)
#define B_LDS() do { \
  asm volatile("s_waitcnt lgkmcnt(0)" ::: "memory"); \
  __builtin_amdgcn_s_barrier(); \
  __builtin_amdgcn_sched_barrier(0); } while (0)

__global__ __launch_bounds__(THREADS, 4) void mdn_main(
    const float* __restrict__ x, const float* __restrict__ t,
    const float* __restrict__ y, const float* __restrict__ Wm,
    const float* __restrict__ bm, const float* __restrict__ Wv,
    const float* __restrict__ bv, const float* __restrict__ Wg,
    const float* __restrict__ bg, float* __restrict__ partials,
    float* __restrict__ out_atomic)
{
  __shared__ float xs[2][TILE_R * DX];     // 2 x 16 KB
  __shared__ float ts[2][TILE_R * DT];     // 2 x 8 KB
  __shared__ float ys[2][TILE_R * MDIM];   // 2 x 4 KB
  __shared__ float ll_s[TILE_R * 17];      // padded [32][17]
  __shared__ float red_s[8];

  const int tid = threadIdx.x;
  const int lane = tid & 63;
  const int wv = tid >> 6;       // wave id == expert k
  const int l15 = lane & 15;
  const int lhi = lane >> 4;     // 0..3
  const int swz3 = l15 & 7;

  // per-lane swizzled read column offsets (floats), shared by xs and ts reads
  const int cA0 = ((lhi * 2 + 0) ^ swz3) * 4;
  const int cA1 = ((lhi * 2 + 1) ^ swz3) * 4;

  // DMA source offsets (pre-swizzled so linear LDS + swizzled read = identity)
  const int ch0 = (wv * 2 + 0) * 64 + lane;
  const int ch1 = (wv * 2 + 1) * 64 + lane;
  const int xr0 = ch0 >> 5, xr1 = ch1 >> 5;
  const int x0off = xr0 * DX + ((((ch0 & 31) ^ (xr0 & 7))) << 2);
  const int x1off = xr1 * DX + ((((ch1 & 31) ^ (xr1 & 7))) << 2);
  const int cht = wv * 64 + lane;
  const int tr0 = cht >> 4;
  const int t0off = tr0 * DT + ((((cht & 15) ^ (tr0 & 7))) << 2);
  const int yr0 = cht >> 3;
  const int y0off = yr0 * MDIM + ((((cht & 7) ^ (yr0 & 7))) << 2);

  const int first = blockIdx.x * TPB;

  auto issue_batch = [&](int tile, int buf) {
    const size_t base = (size_t)tile * TILE_R;
    const float* xb = x + base * DX;
    const float* tb = t + base * DT;
    const float* yb = y + base * MDIM;
    glds16(xb + x0off, &xs[buf][(wv * 2 + 0) * 256]);
    glds16(xb + x1off, &xs[buf][(wv * 2 + 1) * 256]);
    glds16(tb + t0off, &ts[buf][wv * 256]);
    if (wv < 4) glds16(yb + y0off, &ys[buf][wv * 256]);
  };

  issue_batch(first, 0);   // overlap DMA with weight-fragment prologue

  // biases for this wave's expert
  const float bm_lo = bm[wv * MDIM + l15];
  const float bm_hi = bm[wv * MDIM + 16 + l15];
  const float bv_lo = bv[wv * MDIM + l15];
  const float bv_hi = bv[wv * MDIM + 16 + l15];
  const float bg_r = (l15 < KEXP) ? bg[l15] : 0.f;

  // B fragments in registers: ct 0,1 = Wm cols 0..15/16..31; 2,3 = Wv.
  // B layout (16x16x32): k = (lane>>4)*8 + i, col = lane&15.
  bf16x8 bfrag[4][4];
  #pragma unroll
  for (int ct = 0; ct < 4; ++ct) {
    const float* W = (ct < 2 ? Wm : Wv) + (size_t)wv * (DX * MDIM);
    const int mcol = ((ct & 1) << 4) + l15;
    #pragma unroll
    for (int kk = 0; kk < 4; ++kk) {
      bf16x8 tmp;
      #pragma unroll
      for (int i = 0; i < 8; ++i)
        tmp[i] = (__bf16)W[(kk * 32 + lhi * 8 + i) * MDIM + mcol];
      bfrag[ct][kk] = tmp;
    }
  }
  // Gate weight fragments (cols >= KEXP zero-padded)
  bf16x8 wgfrag[2];
  #pragma unroll
  for (int kk = 0; kk < 2; ++kk) {
    bf16x8 tmp;
    #pragma unroll
    for (int i = 0; i < 8; ++i) {
      const int d = kk * 32 + lhi * 8 + i;
      tmp[i] = (__bf16)((l15 < KEXP) ? Wg[d * KEXP + l15] : 0.f);
    }
    wgfrag[kk] = tmp;
  }

  float loss_acc = 0.f;
  const float HL2PI = 0.91893853320467274f;   // 0.5*log(2*pi)

  for (int it = 0; it < TPB; ++it) {
    const int cur = it & 1;
    B_FULL();   // batch(it) landed everywhere; prev reads of buf^1 done
    issue_batch(first + ((it + 1 < TPB) ? it + 1 : it), cur ^ 1);

    const float* xc = xs[cur];
    const float* yc = ys[cur];

    // ---- mean/logvar MFMAs + Gaussian-LL epilogue, per 16-row slab ----
    #pragma unroll
    for (int rt = 0; rt < 2; ++rt) {
      f32x4 acc0 = {0.f,0.f,0.f,0.f}, acc1 = acc0, acc2 = acc0, acc3 = acc0;
      const int rbase = (rt * 16 + l15) * DX;
      #pragma unroll
      for (int kk = 0; kk < 4; ++kk) {
        const f32x4 f0 = *(const f32x4*)&xc[rbase + kk * 32 + cA0];
        const f32x4 f1 = *(const f32x4*)&xc[rbase + kk * 32 + cA1];
        const bf16x8 af = cvt8(f0, f1);
        acc0 = MFMA16(af, bfrag[0][kk], acc0);
        acc1 = MFMA16(af, bfrag[1][kk], acc1);
        acc2 = MFMA16(af, bfrag[2][kk], acc2);
        acc3 = MFMA16(af, bfrag[3][kk], acc3);
      }
      // C/D layout: col = lane&15, row = (lane>>4)*4 + j
      #pragma unroll
      for (int j = 0; j < 4; ++j) {
        const int r = rt * 16 + lhi * 4 + j;
        const int r7 = r & 7;
        const float y0 = yc[r * MDIM + ((((l15 >> 2)    ) ^ r7) << 2) + (l15 & 3)];
        const float y1 = yc[r * MDIM + ((((l15 >> 2) + 4) ^ r7) << 2) + (l15 & 3)];
        const float mean0 = acc0[j] + bm_lo;
        const float mean1 = acc1[j] + bm_hi;
        const float lv0 = acc2[j] + bv_lo;
        const float lv1 = acc3[j] + bv_hi;
        const float d0 = y0 - mean0, d1 = y1 - mean1;
        float s = d0 * d0 * (0.5f * __expf(-lv0)) + 0.5f * lv0
                + d1 * d1 * (0.5f * __expf(-lv1)) + 0.5f * lv1;
        s += __shfl_xor(s, 1);
        s += __shfl_xor(s, 2);
        s += __shfl_xor(s, 4);
        s += __shfl_xor(s, 8);
        if (l15 == 0) ll_s[r * 17 + wv] = -(s + MDIM * HL2PI);
      }
    }
    B_LDS();    // ll_s visible; DMA stays in flight

    // ---- gate via MFMA + per-row double-LSE; wave owns (rt,j) slice ----
    {
      const float* tc = ts[cur];
      const int rtg = wv & 1, jg = wv >> 1;
      const int rb = (rtg * 16 + l15) * DT;
      f32x4 g = {0.f,0.f,0.f,0.f};
      #pragma unroll
      for (int kk = 0; kk < 2; ++kk) {
        const f32x4 f0 = *(const f32x4*)&tc[rb + kk * 32 + cA0];
        const f32x4 f1 = *(const f32x4*)&tc[rb + kk * 32 + cA1];
        g = MFMA16(cvt8(f0, f1), wgfrag[kk], g);
      }
      const int rr = rtg * 16 + lhi * 4 + jg;
      const float logit = g[jg] + bg_r;          // lanes l15>=8: zeros, unused
      const float ll = ll_s[rr * 17 + l15];      // lanes l15>=8: garbage, isolated
      const float a = logit + ll;
      float mg = logit, ma = a;
      mg = fmaxf(mg, __shfl_xor(mg, 1));
      mg = fmaxf(mg, __shfl_xor(mg, 2));
      mg = fmaxf(mg, __shfl_xor(mg, 4));
      ma = fmaxf(ma, __shfl_xor(ma, 1));
      ma = fmaxf(ma, __shfl_xor(ma, 2));
      ma = fmaxf(ma, __shfl_xor(ma, 4));
      float eg = __expf(logit - mg);
      float ea = __expf(a - ma);
      eg += __shfl_xor(eg, 1); eg += __shfl_xor(eg, 2); eg += __shfl_xor(eg, 4);
      ea += __shfl_xor(ea, 1); ea += __shfl_xor(ea, 2); ea += __shfl_xor(ea, 4);
      if (l15 == 0) loss_acc += (mg + __logf(eg)) - (ma + __logf(ea));
    }
  }

  // block reduction of loss
  loss_acc += __shfl_xor(loss_acc, 1);
  loss_acc += __shfl_xor(loss_acc, 2);
  loss_acc += __shfl_xor(loss_acc, 4);
  loss_acc += __shfl_xor(loss_acc, 8);
  loss_acc += __shfl_xor(loss_acc, 16);
  loss_acc += __shfl_xor(loss_acc, 32);
  if (lane == 0) red_s[wv] = loss_acc;
  __syncthreads();
  if (tid == 0) {
    float s = 0.f;
    #pragma unroll
    for (int w = 0; w < 8; ++w) s += red_s[w];
    if (partials) partials[blockIdx.x] = s;
    else atomicAdd(out_atomic, s);
  }
}

__global__ void mdn_reg(const float* __restrict__ Wm, const float* __restrict__ Wv,
                        const float* __restrict__ Wg, float* __restrict__ partials,
                        float* __restrict__ out_atomic)
{
  __shared__ float red[4];
  const int gid = blockIdx.x * 256 + threadIdx.x;
  const int stride = 64 * 256;
  float s = 0.f;
  for (int i = gid; i < DX * MDIM * KEXP; i += stride) { float w = Wm[i]; s += w * w; }
  for (int i = gid; i < DX * MDIM * KEXP; i += stride) { float w = Wv[i]; s += w * w; }
  for (int i = gid; i < DT * KEXP; i += stride)        { float w = Wg[i]; s += w * w; }
  s += __shfl_xor(s, 1);
  s += __shfl_xor(s, 2);
  s += __shfl_xor(s, 4);
  s += __shfl_xor(s, 8);
  s += __shfl_xor(s, 16);
  s += __shfl_xor(s, 32);
  if ((threadIdx.x & 63) == 0) red[threadIdx.x >> 6] = s;
  __syncthreads();
  if (threadIdx.x == 0) {
    float b = red[0] + red[1] + red[2] + red[3];
    if (partials) partials[GRID_MAIN + blockIdx.x] = b;
    else atomicAdd(out_atomic, b);
  }
}

__global__ void mdn_final(const float* __restrict__ partials, float* __restrict__ out)
{
  __shared__ float red[4];
  float s = 0.f;
  for (int i = threadIdx.x; i < GRID_MAIN + 64; i += 256) s += partials[i];
  s += __shfl_xor(s, 1);
  s += __shfl_xor(s, 2);
  s += __shfl_xor(s, 4);
  s += __shfl_xor(s, 8);
  s += __shfl_xor(s, 16);
  s += __shfl_xor(s, 32);
  if ((threadIdx.x & 63) == 0) red[threadIdx.x >> 6] = s;
  __syncthreads();
  if (threadIdx.x == 0) out[0] = red[0] + red[1] + red[2] + red[3];
}

extern "C" void kernel_launch(void* const* d_in, const int* in_sizes, int n_in,
                              void* d_out, int out_size, void* d_ws, size_t ws_size,
                              hipStream_t stream)
{
  const float* x  = (const float*)d_in[0];
  const float* t  = (const float*)d_in[1];
  const float* y  = (const float*)d_in[2];
  const float* Wm = (const float*)d_in[3];
  const float* bm = (const float*)d_in[4];
  const float* Wv = (const float*)d_in[5];
  const float* bv = (const float*)d_in[6];
  const float* Wg = (const float*)d_in[7];
  const float* bg = (const float*)d_in[8];
  float* out = (float*)d_out;

  if (ws_size >= (GRID_MAIN + 64) * sizeof(float)) {
    float* partials = (float*)d_ws;
    mdn_main<<<GRID_MAIN, THREADS, 0, stream>>>(x, t, y, Wm, bm, Wv, bv, Wg, bg,
                                                partials, nullptr);
    mdn_reg<<<64, 256, 0, stream>>>(Wm, Wv, Wg, partials, nullptr);
    mdn_final<<<1, 256, 0, stream>>>(partials, out);
  } else {
    hipMemsetAsync(out, 0, sizeof(float), stream);
    mdn_main<<<GRID_MAIN, THREADS, 0, stream>>>(x, t, y, Wm, bm, Wv, bv, Wg, bg,
                                                nullptr, out);
    mdn_reg<<<64, 256, 0, stream>>>(Wm, Wv, Wg, nullptr, out);
  }
}

// Round 3
// 273.432 us; speedup vs baseline: 1.4902x; 1.1023x over previous
//
#include <hip/hip_runtime.h>
#include <hip/hip_bf16.h>

// MDN NLL, fully fused. N=524288 Dx=128 Dt=64 M=32 K=8.
// Memory-bound target: 470 MB reads -> ~75us floor at 6.3 TB/s.
// Pipeline: all inputs staged f32 via global_load_lds (dbuf, issued 1 iter
// ahead), raw s_barrier + manual waitcnt (no vmcnt drains mid-iter),
// source-pre-swizzled chunks for conflict-free ds_read_b128.
// R2 lesson: launch_bounds(512,4) forced 64 VGPR -> bfrag spilled (115 MB
// scratch writes). LDS caps us at 2 blocks/CU anyway -> (512,2), 128 VGPR.

#define NN 524288
#define DX 128
#define DT 64
#define MDIM 32
#define KEXP 8
#define TILE_R 32
#define THREADS 512
#define GRID_MAIN 512
#define TILES_TOTAL (NN / TILE_R)        // 16384
#define TPB (TILES_TOTAL / GRID_MAIN)    // 32

typedef __bf16 bf16x8 __attribute__((ext_vector_type(8)));
typedef float f32x4 __attribute__((ext_vector_type(4)));

__device__ __forceinline__ void glds16(const float* g, float* l) {
  __builtin_amdgcn_global_load_lds(
      (const __attribute__((address_space(1))) unsigned int*)g,
      (__attribute__((address_space(3))) unsigned int*)l, 16, 0, 0);
}

__device__ __forceinline__ bf16x8 cvt8(const f32x4 a, const f32x4 b) {
  bf16x8 r;
  r[0] = (__bf16)a[0]; r[1] = (__bf16)a[1]; r[2] = (__bf16)a[2]; r[3] = (__bf16)a[3];
  r[4] = (__bf16)b[0]; r[5] = (__bf16)b[1]; r[6] = (__bf16)b[2]; r[7] = (__bf16)b[3];
  return r;
}

#define MFMA16(a, b, c) __builtin_amdgcn_mfma_f32_16x16x32_bf16(a, b, c, 0, 0, 0)

// Raw barriers: keep DMA in flight where safe (rule 18: sched_barrier after).
#define B_FULL() do { \
  asm volatile("s_waitcnt vmcnt(0) lgkmcnt(0)" ::: "memory"); \
  __builtin_amdgcn_s_barrier(); \
  __builtin_amdgcn_sched_barrier(0); } while (0)
#define B_LDS() do { \
  asm volatile("s_waitcnt lgkmcnt(0)" ::: "memory"); \
  __builtin_amdgcn_s_barrier(); \
  __builtin_amdgcn_sched_barrier(0); } while (0)

__global__ __launch_bounds__(THREADS, 2) void mdn_main(
    const float* __restrict__ x, const float* __restrict__ t,
    const float* __restrict__ y, const float* __restrict__ Wm,
    const float* __restrict__ bm, const float* __restrict__ Wv,
    const float* __restrict__ bv, const float* __restrict__ Wg,
    const float* __restrict__ bg, float* __restrict__ partials,
    float* __restrict__ out_atomic)
{
  __shared__ float xs[2][TILE_R * DX];     // 2 x 16 KB
  __shared__ float ts[2][TILE_R * DT];     // 2 x 8 KB
  __shared__ float ys[2][TILE_R * MDIM];   // 2 x 4 KB
  __shared__ float ll_s[TILE_R * 17];      // padded [32][17]
  __shared__ float red_s[8];

  const int tid = threadIdx.x;
  const int lane = tid & 63;
  const int wv = tid >> 6;       // wave id == expert k
  const int l15 = lane & 15;
  const int lhi = lane >> 4;     // 0..3

  // per-lane swizzled read column offsets (floats), shared by xs and ts reads
  const int cA0 = ((lhi * 2 + 0) ^ (l15 & 7)) * 4;
  const int cA1 = ((lhi * 2 + 1) ^ (l15 & 7)) * 4;

  // DMA source offsets (pre-swizzled so linear LDS + swizzled read = identity)
  const int ch0 = (wv * 2 + 0) * 64 + lane;
  const int ch1 = (wv * 2 + 1) * 64 + lane;
  const int xr0 = ch0 >> 5, xr1 = ch1 >> 5;
  const int x0off = xr0 * DX + ((((ch0 & 31) ^ (xr0 & 7))) << 2);
  const int x1off = xr1 * DX + ((((ch1 & 31) ^ (xr1 & 7))) << 2);
  const int cht = wv * 64 + lane;
  const int tr0 = cht >> 4;
  const int t0off = tr0 * DT + ((((cht & 15) ^ (tr0 & 7))) << 2);
  const int yr0 = cht >> 3;
  const int y0off = yr0 * MDIM + ((((cht & 7) ^ (yr0 & 7))) << 2);

  const int first = blockIdx.x * TPB;

  auto issue_batch = [&](int tile, int buf) {
    const size_t base = (size_t)tile * TILE_R;
    const float* xb = x + base * DX;
    const float* tb = t + base * DT;
    const float* yb = y + base * MDIM;
    glds16(xb + x0off, &xs[buf][(wv * 2 + 0) * 256]);
    glds16(xb + x1off, &xs[buf][(wv * 2 + 1) * 256]);
    glds16(tb + t0off, &ts[buf][wv * 256]);
    if (wv < 4) glds16(yb + y0off, &ys[buf][wv * 256]);
  };

  issue_batch(first, 0);   // overlap DMA with weight-fragment prologue

  // biases for this wave's expert
  const float bm_lo = bm[wv * MDIM + l15];
  const float bm_hi = bm[wv * MDIM + 16 + l15];
  const float bv_lo = bv[wv * MDIM + l15];
  const float bv_hi = bv[wv * MDIM + 16 + l15];
  const float bg_r = (l15 < KEXP) ? bg[l15] : 0.f;

  // B fragments in registers: ct 0,1 = Wm cols 0..15/16..31; 2,3 = Wv.
  // B layout (16x16x32): k = (lane>>4)*8 + i, col = lane&15.
  bf16x8 bfrag[4][4];
  #pragma unroll
  for (int ct = 0; ct < 4; ++ct) {
    const float* W = (ct < 2 ? Wm : Wv) + (size_t)wv * (DX * MDIM);
    const int mcol = ((ct & 1) << 4) + l15;
    #pragma unroll
    for (int kk = 0; kk < 4; ++kk) {
      bf16x8 tmp;
      #pragma unroll
      for (int i = 0; i < 8; ++i)
        tmp[i] = (__bf16)W[(kk * 32 + lhi * 8 + i) * MDIM + mcol];
      bfrag[ct][kk] = tmp;
    }
  }
  // Gate weight fragments (cols >= KEXP zero-padded)
  bf16x8 wgfrag[2];
  #pragma unroll
  for (int kk = 0; kk < 2; ++kk) {
    bf16x8 tmp;
    #pragma unroll
    for (int i = 0; i < 8; ++i) {
      const int d = kk * 32 + lhi * 8 + i;
      tmp[i] = (__bf16)((l15 < KEXP) ? Wg[d * KEXP + l15] : 0.f);
    }
    wgfrag[kk] = tmp;
  }

  float loss_acc = 0.f;
  const float HL2PI = 0.91893853320467274f;   // 0.5*log(2*pi)

  for (int it = 0; it < TPB; ++it) {
    const int cur = it & 1;
    B_FULL();   // batch(it) landed everywhere; prev reads of buf^1 done
    issue_batch(first + ((it + 1 < TPB) ? it + 1 : it), cur ^ 1);

    const float* xc = xs[cur];
    const float* yc = ys[cur];

    // ---- mean/logvar MFMAs + Gaussian-LL epilogue, per 16-row slab ----
    #pragma unroll
    for (int rt = 0; rt < 2; ++rt) {
      f32x4 acc0 = {0.f,0.f,0.f,0.f}, acc1 = acc0, acc2 = acc0, acc3 = acc0;
      const int rbase = (rt * 16 + l15) * DX;
      #pragma unroll
      for (int kk = 0; kk < 4; ++kk) {
        const f32x4 f0 = *(const f32x4*)&xc[rbase + kk * 32 + cA0];
        const f32x4 f1 = *(const f32x4*)&xc[rbase + kk * 32 + cA1];
        const bf16x8 af = cvt8(f0, f1);
        acc0 = MFMA16(af, bfrag[0][kk], acc0);
        acc1 = MFMA16(af, bfrag[1][kk], acc1);
        acc2 = MFMA16(af, bfrag[2][kk], acc2);
        acc3 = MFMA16(af, bfrag[3][kk], acc3);
      }
      // C/D layout: col = lane&15, row = (lane>>4)*4 + j
      #pragma unroll
      for (int j = 0; j < 4; ++j) {
        const int r = rt * 16 + lhi * 4 + j;
        const int r7 = r & 7;
        const float y0 = yc[r * MDIM + ((((l15 >> 2)    ) ^ r7) << 2) + (l15 & 3)];
        const float y1 = yc[r * MDIM + ((((l15 >> 2) + 4) ^ r7) << 2) + (l15 & 3)];
        const float mean0 = acc0[j] + bm_lo;
        const float mean1 = acc1[j] + bm_hi;
        const float lv0 = acc2[j] + bv_lo;
        const float lv1 = acc3[j] + bv_hi;
        const float d0 = y0 - mean0, d1 = y1 - mean1;
        float s = d0 * d0 * (0.5f * __expf(-lv0)) + 0.5f * lv0
                + d1 * d1 * (0.5f * __expf(-lv1)) + 0.5f * lv1;
        s += __shfl_xor(s, 1);
        s += __shfl_xor(s, 2);
        s += __shfl_xor(s, 4);
        s += __shfl_xor(s, 8);
        if (l15 == 0) ll_s[r * 17 + wv] = -(s + MDIM * HL2PI);
      }
    }
    B_LDS();    // ll_s visible; DMA stays in flight

    // ---- gate via MFMA + per-row double-LSE; wave owns (rt,j) slice ----
    {
      const float* tc = ts[cur];
      const int rtg = wv & 1, jg = wv >> 1;
      const int rb = (rtg * 16 + l15) * DT;
      f32x4 g = {0.f,0.f,0.f,0.f};
      #pragma unroll
      for (int kk = 0; kk < 2; ++kk) {
        const f32x4 f0 = *(const f32x4*)&tc[rb + kk * 32 + cA0];
        const f32x4 f1 = *(const f32x4*)&tc[rb + kk * 32 + cA1];
        g = MFMA16(cvt8(f0, f1), wgfrag[kk], g);
      }
      const int rr = rtg * 16 + lhi * 4 + jg;
      const float logit = g[jg] + bg_r;          // lanes l15>=8: zeros, unused
      const float ll = ll_s[rr * 17 + l15];      // lanes l15>=8: garbage, isolated
      const float a = logit + ll;
      float mg = logit, ma = a;
      mg = fmaxf(mg, __shfl_xor(mg, 1));
      mg = fmaxf(mg, __shfl_xor(mg, 2));
      mg = fmaxf(mg, __shfl_xor(mg, 4));
      ma = fmaxf(ma, __shfl_xor(ma, 1));
      ma = fmaxf(ma, __shfl_xor(ma, 2));
      ma = fmaxf(ma, __shfl_xor(ma, 4));
      float eg = __expf(logit - mg);
      float ea = __expf(a - ma);
      eg += __shfl_xor(eg, 1); eg += __shfl_xor(eg, 2); eg += __shfl_xor(eg, 4);
      ea += __shfl_xor(ea, 1); ea += __shfl_xor(ea, 2); ea += __shfl_xor(ea, 4);
      if (l15 == 0) loss_acc += (mg + __logf(eg)) - (ma + __logf(ea));
    }
  }

  // block reduction of loss
  loss_acc += __shfl_xor(loss_acc, 1);
  loss_acc += __shfl_xor(loss_acc, 2);
  loss_acc += __shfl_xor(loss_acc, 4);
  loss_acc += __shfl_xor(loss_acc, 8);
  loss_acc += __shfl_xor(loss_acc, 16);
  loss_acc += __shfl_xor(loss_acc, 32);
  if (lane == 0) red_s[wv] = loss_acc;
  __syncthreads();
  if (tid == 0) {
    float s = 0.f;
    #pragma unroll
    for (int w = 0; w < 8; ++w) s += red_s[w];
    if (partials) partials[blockIdx.x] = s;
    else atomicAdd(out_atomic, s);
  }
}

__global__ void mdn_reg(const float* __restrict__ Wm, const float* __restrict__ Wv,
                        const float* __restrict__ Wg, float* __restrict__ partials,
                        float* __restrict__ out_atomic)
{
  __shared__ float red[4];
  const int gid = blockIdx.x * 256 + threadIdx.x;
  const int stride = 64 * 256;
  float s = 0.f;
  for (int i = gid; i < DX * MDIM * KEXP; i += stride) { float w = Wm[i]; s += w * w; }
  for (int i = gid; i < DX * MDIM * KEXP; i += stride) { float w = Wv[i]; s += w * w; }
  for (int i = gid; i < DT * KEXP; i += stride)        { float w = Wg[i]; s += w * w; }
  s += __shfl_xor(s, 1);
  s += __shfl_xor(s, 2);
  s += __shfl_xor(s, 4);
  s += __shfl_xor(s, 8);
  s += __shfl_xor(s, 16);
  s += __shfl_xor(s, 32);
  if ((threadIdx.x & 63) == 0) red[threadIdx.x >> 6] = s;
  __syncthreads();
  if (threadIdx.x == 0) {
    float b = red[0] + red[1] + red[2] + red[3];
    if (partials) partials[GRID_MAIN + blockIdx.x] = b;
    else atomicAdd(out_atomic, b);
  }
}

__global__ void mdn_final(const float* __restrict__ partials, float* __restrict__ out)
{
  __shared__ float red[4];
  float s = 0.f;
  for (int i = threadIdx.x; i < GRID_MAIN + 64; i += 256) s += partials[i];
  s += __shfl_xor(s, 1);
  s += __shfl_xor(s, 2);
  s += __shfl_xor(s, 4);
  s += __shfl_xor(s, 8);
  s += __shfl_xor(s, 16);
  s += __shfl_xor(s, 32);
  if ((threadIdx.x & 63) == 0) red[threadIdx.x >> 6] = s;
  __syncthreads();
  if (threadIdx.x == 0) out[0] = red[0] + red[1] + red[2] + red[3];
}

extern "C" void kernel_launch(void* const* d_in, const int* in_sizes, int n_in,
                              void* d_out, int out_size, void* d_ws, size_t ws_size,
                              hipStream_t stream)
{
  const float* x  = (const float*)d_in[0];
  const float* t  = (const float*)d_in[1];
  const float* y  = (const float*)d_in[2];
  const float* Wm = (const float*)d_in[3];
  const float* bm = (const float*)d_in[4];
  const float* Wv = (const float*)d_in[5];
  const float* bv = (const float*)d_in[6];
  const float* Wg = (const float*)d_in[7];
  const float* bg = (const float*)d_in[8];
  float* out = (float*)d_out;

  if (ws_size >= (GRID_MAIN + 64) * sizeof(float)) {
    float* partials = (float*)d_ws;
    mdn_main<<<GRID_MAIN, THREADS, 0, stream>>>(x, t, y, Wm, bm, Wv, bv, Wg, bg,
                                                partials, nullptr);
    mdn_reg<<<64, 256, 0, stream>>>(Wm, Wv, Wg, partials, nullptr);
    mdn_final<<<1, 256, 0, stream>>>(partials, out);
  } else {
    hipMemsetAsync(out, 0, sizeof(float), stream);
    mdn_main<<<GRID_MAIN, THREADS, 0, stream>>>(x, t, y, Wm, bm, Wv, bv, Wg, bg,
                                                nullptr, out);
    mdn_reg<<<64, 256, 0, stream>>>(Wm, Wv, Wg, nullptr, out);
  }
}